// Round 1
// baseline (6331.846 us; speedup 1.0000x reference)
//
#include <hip/hip_runtime.h>
#include <math.h>

#define HW 4096   // 64*64
#define CCH 128
#define NBATCH 4

// ---------------- conv 1x1 (GEMM over channels), optional relu+affine, optional residual add
__global__ void conv1x1_kernel(const float* __restrict__ in, const float* __restrict__ w,
                               const float* __restrict__ bias, float* __restrict__ out,
                               int CI, int CO, int do_affine,
                               const float* __restrict__ s, const float* __restrict__ o,
                               const float* __restrict__ addbuf)
{
    __shared__ float wl[256];
    int co = blockIdx.y, b = blockIdx.z;
    int p = blockIdx.x * 256 + threadIdx.x;
    for (int i = threadIdx.x; i < CI; i += 256) wl[i] = w[co * CI + i];
    __syncthreads();
    float acc = bias[co];
    const float* inb = in + (size_t)b * CI * HW + p;
    for (int ci = 0; ci < CI; ++ci) acc += wl[ci] * inb[(size_t)ci * HW];
    if (do_affine) acc = fmaxf(acc, 0.f) * s[co] + o[co];
    size_t oidx = ((size_t)(b * CO + co)) * HW + p;
    if (addbuf) acc += addbuf[oidx];
    out[oidx] = acc;
}

// ---------------- KxK conv (pad), optional relu+affine. Weight row staged in LDS.
__global__ void convk_kernel(const float* __restrict__ in, const float* __restrict__ w,
                             const float* __restrict__ bias, float* __restrict__ out,
                             int CI, int OB, int co_off, int K, int pad,
                             int do_affine, const float* __restrict__ s, const float* __restrict__ o)
{
    extern __shared__ float wl[];   // CI*K*K floats
    int co = blockIdx.y, b = blockIdx.z;
    int nw = CI * K * K;
    for (int i = threadIdx.x; i < nw; i += 256) wl[i] = w[co * nw + i];
    __syncthreads();
    int p = blockIdx.x * 256 + threadIdx.x;
    int h = p >> 6, x = p & 63;
    float acc = bias[co];
    const float* inb = in + (size_t)b * CI * HW;
    for (int ci = 0; ci < CI; ++ci) {
        const float* ic = inb + (size_t)ci * HW;
        const float* wc = wl + ci * K * K;
        for (int kh = 0; kh < K; ++kh) {
            int hi = h + kh - pad;
            if ((unsigned)hi >= 64u) continue;
            const float* irow = ic + hi * 64;
            for (int kw = 0; kw < K; ++kw) {
                int wi = x + kw - pad;
                if ((unsigned)wi >= 64u) continue;
                acc += wc[kh * K + kw] * irow[wi];
            }
        }
    }
    if (do_affine) acc = fmaxf(acc, 0.f) * s[co] + o[co];
    out[((size_t)(b * OB + co_off + co)) * HW + p] = acc;
}

// ---------------- cosine similarity over groups of 128 consecutive floats (flat reshape view)
__global__ void sim_kernel(const float* __restrict__ r1, const float* __restrict__ r2,
                           float* __restrict__ sim)
{
    int gw = blockIdx.x * 4 + (threadIdx.x >> 6);   // global group index, 4 waves/block
    int lane = threadIdx.x & 63;
    int b = gw >> 12, n = gw & 4095;
    const float* p1 = r1 + (size_t)b * 524288 + (size_t)n * 128;
    const float* p2 = r2 + (size_t)b * 524288 + (size_t)n * 128;
    float a0 = p1[lane], a1 = p1[lane + 64];
    float b0 = p2[lane], b1 = p2[lane + 64];
    float dot = a0 * b0 + a1 * b1;
    float n1 = a0 * a0 + a1 * a1;
    float n2 = b0 * b0 + b1 * b1;
    for (int m = 32; m; m >>= 1) {
        dot += __shfl_xor(dot, m);
        n1  += __shfl_xor(n1, m);
        n2  += __shfl_xor(n2, m);
    }
    if (lane == 0) sim[b * 4096 + n] = dot / fmaxf(sqrtf(n1) * sqrtf(n2), 1e-8f);
}

// ---------------- x = concat(dif1, dif2) in [B][256][HW]
__global__ void x_kernel(const float* __restrict__ r1, const float* __restrict__ r2,
                         const float* __restrict__ sim, float* __restrict__ xo)
{
    size_t i = (size_t)blockIdx.x * 256 + threadIdx.x;   // [B][256][4096]
    int p = (int)(i & 4095);
    int cc = (int)((i >> 12) & 255);
    int b = (int)(i >> 20);
    int c = cc & 127;
    const float* R = (cc & 128) ? r2 : r1;
    const float* Rb = R + (size_t)b * 524288;
    float sv = sim[b * 4096 + p];
    xo[i] = Rb[(size_t)p * 128 + c] * (1.f - sv) + Rb[(size_t)c * 4096 + p];
}

// ---------------- simp = avgpool2(|sim1 - sim2|) in [B][128][32][32]
__global__ void simp_kernel(const float* __restrict__ r1, const float* __restrict__ r2,
                            const float* __restrict__ sim, float* __restrict__ simp)
{
    int i = blockIdx.x * 256 + threadIdx.x;   // B*128*1024 = 524288
    int w2 = i & 31, h2 = (i >> 5) & 31, c = (i >> 10) & 127, b = i >> 17;
    const float* R1 = r1 + (size_t)b * 524288;
    const float* R2 = r2 + (size_t)b * 524288;
    const float* sb = sim + b * 4096;
    float acc = 0.f;
    for (int dh = 0; dh < 2; ++dh)
        for (int dw = 0; dw < 2; ++dw) {
            int p = (2 * h2 + dh) * 64 + (2 * w2 + dw);
            float d = (R1[(size_t)p * 128 + c] - R2[(size_t)p * 128 + c]) * sb[p]
                    + (R1[(size_t)c * 4096 + p] - R2[(size_t)c * 4096 + p]);
            acc += fabsf(d);
        }
    simp[i] = acc * 0.25f;
}

// ---------------- attention GEMM1: S[n,m] = sum_c attn[n,c]*inc[c,m]   (per batch/branch)
__global__ void attn_gemm1(const float* __restrict__ attn, const float* __restrict__ inc,
                           float* __restrict__ S)
{
    __shared__ float ar[128];
    int n = blockIdx.y;
    int m = blockIdx.x * 256 + threadIdx.x;
    if (threadIdx.x < 128) ar[threadIdx.x] = attn[n * 128 + threadIdx.x];
    __syncthreads();
    float acc = 0.f;
    for (int c = 0; c < 128; ++c) acc += ar[c] * inc[(size_t)c * HW + m];
    S[(size_t)n * HW + m] = acc;
}

// ---------------- softmax over rows of 4096
__global__ void softmax_kernel(float* __restrict__ S)
{
    __shared__ float red[256];
    float* row = S + (size_t)blockIdx.x * HW;
    int t = threadIdx.x;
    float mx = -1e30f;
    for (int i = t; i < HW; i += 256) mx = fmaxf(mx, row[i]);
    red[t] = mx; __syncthreads();
    for (int s2 = 128; s2; s2 >>= 1) { if (t < s2) red[t] = fmaxf(red[t], red[t + s2]); __syncthreads(); }
    mx = red[0]; __syncthreads();
    float sum = 0.f;
    for (int i = t; i < HW; i += 256) { float e = __expf(row[i] - mx); row[i] = e; sum += e; }
    red[t] = sum; __syncthreads();
    for (int s2 = 128; s2; s2 >>= 1) { if (t < s2) red[t] += red[t + s2]; __syncthreads(); }
    float inv = 1.f / red[0];
    for (int i = t; i < HW; i += 256) row[i] *= inv;
}

// ---------------- attention GEMM2: out[c,m] = sum_n attn[n,c]*P[n,m] + inc[c,m]
__global__ void attn_gemm2(const float* __restrict__ attn, const float* __restrict__ P,
                           const float* __restrict__ inc, float* __restrict__ outp)
{
    int m = blockIdx.x * 256 + threadIdx.x;
    int c0 = blockIdx.y * 8;
    float acc[8] = {0, 0, 0, 0, 0, 0, 0, 0};
    for (int n = 0; n < 1024; ++n) {
        float pv = P[(size_t)n * HW + m];
        const float* an = attn + n * 128 + c0;
#pragma unroll
        for (int k = 0; k < 8; ++k) acc[k] += an[k] * pv;
    }
#pragma unroll
    for (int k = 0; k < 8; ++k)
        outp[(size_t)(c0 + k) * HW + m] = acc[k] + inc[(size_t)(c0 + k) * HW + m];
}

// ---------------- bilinear 2x upsample, half-pixel centers, edge clamp
__global__ void upsample_kernel(const float* __restrict__ in, float* __restrict__ out)
{
    int i = blockIdx.x * 256 + threadIdx.x;   // [BC=512][128][128]
    int x = i & 127, y = (i >> 7) & 127, bc = i >> 14;
    const float* ib = in + (size_t)bc * HW;
    float sy = 0.5f * y - 0.25f;
    float sx = 0.5f * x - 0.25f;
    int y0 = (int)floorf(sy); float ty = sy - y0;
    int x0 = (int)floorf(sx); float tx = sx - x0;
    int y0c = min(max(y0, 0), 63), y1c = min(max(y0 + 1, 0), 63);
    int x0c = min(max(x0, 0), 63), x1c = min(max(x0 + 1, 0), 63);
    float v00 = ib[y0c * 64 + x0c], v01 = ib[y0c * 64 + x1c];
    float v10 = ib[y1c * 64 + x0c], v11 = ib[y1c * 64 + x1c];
    out[i] = (1.f - ty) * ((1.f - tx) * v00 + tx * v01) + ty * ((1.f - tx) * v10 + tx * v11);
}

extern "C" void kernel_launch(void* const* d_in, const int* in_sizes, int n_in,
                              void* d_out, int out_size, void* d_ws, size_t ws_size,
                              hipStream_t stream)
{
    const float* t1       = (const float*)d_in[0];
    const float* t2       = (const float*)d_in[1];
    const float* t1_w     = (const float*)d_in[2];
    const float* t1_b     = (const float*)d_in[3];
    const float* t2_w     = (const float*)d_in[4];
    const float* t2_b     = (const float*)d_in[5];
    const float* df_res_w = (const float*)d_in[6];
    const float* df_res_b = (const float*)d_in[7];
    const float* df_res_s = (const float*)d_in[8];
    const float* df_res_o = (const float*)d_in[9];
    const float* df_b0_w  = (const float*)d_in[10];
    const float* df_b0_b  = (const float*)d_in[11];
    const float* df_b0_s  = (const float*)d_in[12];
    const float* df_b0_o  = (const float*)d_in[13];
    const float* df_b1_w  = (const float*)d_in[14];
    const float* df_b1_b  = (const float*)d_in[15];
    const float* df_b1_s  = (const float*)d_in[16];
    const float* df_b1_o  = (const float*)d_in[17];
    const float* df_fu_w  = (const float*)d_in[18];
    const float* df_fu_b  = (const float*)d_in[19];
    const float* df_fu_s  = (const float*)d_in[20];
    const float* df_fu_o  = (const float*)d_in[21];
    const float* br1_w    = (const float*)d_in[22];
    const float* br1_b    = (const float*)d_in[23];
    const float* br2_w    = (const float*)d_in[24];
    const float* br2_b    = (const float*)d_in[25];
    const float* fu_w     = (const float*)d_in[26];
    const float* fu_b     = (const float*)d_in[27];
    const float* fu_s     = (const float*)d_in[28];
    const float* fu_o     = (const float*)d_in[29];

    float* ws = (float*)d_ws;
    float* res1 = ws;                   // 2,097,152  -> later r -> later inc1
    float* res2 = ws + 2097152;         // 2,097,152  -> later b01 -> later inc2
    float* xbuf = ws + 4194304;         // 4,194,304  (x; later dif at xbuf, fused at xbuf+2M)
    float* Sbuf = ws + 8388608;         // 4,194,304  scores scratch per (b,branch)
    float* abuf = ws + 12582912;        // 4,194,304  concat(a1,a2) [B][256][HW]
    float* simp = ws + 16777216;        // 524,288
    float* simv = ws + 17301504;        // 16,384

    dim3 blk(256);

    // res1/res2 = 1x1 conv(t1/t2)
    conv1x1_kernel<<<dim3(16, 128, 4), blk, 0, stream>>>(t1, t1_w, t1_b, res1, 256, 128, 0, nullptr, nullptr, nullptr);
    conv1x1_kernel<<<dim3(16, 128, 4), blk, 0, stream>>>(t2, t2_w, t2_b, res2, 256, 128, 0, nullptr, nullptr, nullptr);
    // cosine sim over flat groups of 128
    sim_kernel<<<4096, blk, 0, stream>>>(res1, res2, simv);
    // x = concat(dif1,dif2); simp = avgpool2(|sim1-sim2|)
    x_kernel<<<16384, blk, 0, stream>>>(res1, res2, simv, xbuf);
    simp_kernel<<<2048, blk, 0, stream>>>(res1, res2, simv, simp);
    // r = stdconv1x1(x)  -> res1 slot
    conv1x1_kernel<<<dim3(16, 128, 4), blk, 0, stream>>>(xbuf, df_res_w, df_res_b, res1, 256, 128, 1, df_res_s, df_res_o, nullptr);
    // b0 (3x3) -> res2 ch0..63 ; b1 (5x5) -> res2 ch64..127
    convk_kernel<<<dim3(16, 64, 4), blk, 128 * 9 * 4, stream>>>(res1, df_b0_w, df_b0_b, res2, 128, 128, 0, 3, 1, 1, df_b0_s, df_b0_o);
    convk_kernel<<<dim3(16, 64, 4), blk, 128 * 25 * 4, stream>>>(res1, df_b1_w, df_b1_b, res2, 128, 128, 64, 5, 2, 1, df_b1_s, df_b1_o);
    // dif = stdconv1x1(b01) + r   -> xbuf (x dead)
    conv1x1_kernel<<<dim3(16, 128, 4), blk, 0, stream>>>(res2, df_fu_w, df_fu_b, xbuf, 128, 128, 1, df_fu_s, df_fu_o, res1);
    // inc1 = conv3x3(dif) -> res1 ; inc2 = conv5x5(dif) -> res2
    convk_kernel<<<dim3(16, 128, 4), blk, 128 * 9 * 4, stream>>>(xbuf, br1_w, br1_b, res1, 128, 128, 0, 3, 1, 0, nullptr, nullptr);
    convk_kernel<<<dim3(16, 128, 4), blk, 128 * 25 * 4, stream>>>(xbuf, br2_w, br2_b, res2, 128, 128, 0, 5, 2, 0, nullptr, nullptr);
    // dual-branch attention
    for (int br = 0; br < 2; ++br) {
        const float* incb = br ? res2 : res1;
        for (int b = 0; b < 4; ++b) {
            const float* at = simp + (size_t)b * 131072;
            const float* ib = incb + (size_t)b * 524288;
            attn_gemm1<<<dim3(16, 1024), blk, 0, stream>>>(at, ib, Sbuf);
            softmax_kernel<<<1024, blk, 0, stream>>>(Sbuf);
            attn_gemm2<<<dim3(16, 16), blk, 0, stream>>>(at, Sbuf, ib,
                abuf + ((size_t)b * 256 + (size_t)br * 128) * 4096);
        }
    }
    // fused = stdconv1x1(concat(a1,a2)) + dif  -> xbuf + 2M
    float* dif = xbuf;
    float* fused = xbuf + 2097152;
    conv1x1_kernel<<<dim3(16, 128, 4), blk, 0, stream>>>(abuf, fu_w, fu_b, fused, 256, 128, 1, fu_s, fu_o, dif);
    // bilinear 2x upsample -> d_out
    upsample_kernel<<<32768, blk, 0, stream>>>(fused, (float*)d_out);
}

// Round 2
// 3086.552 us; speedup vs baseline: 2.0514x; 2.0514x over previous
//
#include <hip/hip_runtime.h>
#include <math.h>

#define HW 4096   // 64*64

// ---------------- 1x1 conv, register-blocked: each thread computes COT output
// channels for one pixel; weights via wave-uniform (scalar) loads.
template<int COT>
__global__ void __launch_bounds__(256, 2)
conv1x1_tiled(const float* __restrict__ in, const float* __restrict__ w,
              const float* __restrict__ bias, float* __restrict__ out,
              int CI, int CO, int do_affine,
              const float* __restrict__ s, const float* __restrict__ o,
              const float* __restrict__ addbuf)
{
    int m = blockIdx.x * 256 + threadIdx.x;
    int c0 = blockIdx.y * COT;
    int b = blockIdx.z;
    float acc[COT];
#pragma unroll
    for (int k = 0; k < COT; ++k) acc[k] = bias[c0 + k];
    const float* inb = in + (size_t)b * CI * HW + m;
#pragma unroll 4
    for (int ci = 0; ci < CI; ++ci) {
        float v = inb[(size_t)ci * HW];
#pragma unroll
        for (int k = 0; k < COT; ++k) acc[k] += w[(c0 + k) * CI + ci] * v;
    }
#pragma unroll
    for (int k = 0; k < COT; ++k) {
        float v = acc[k];
        if (do_affine) v = fmaxf(v, 0.f) * s[c0 + k] + o[c0 + k];
        size_t oidx = ((size_t)(b * CO + c0 + k)) * HW + m;
        if (addbuf) v += addbuf[oidx];
        out[oidx] = v;
    }
}

// ---------------- KxK conv, tiled: block = 4 rows x 64 cols x COT channels.
// Input tile (with zero halo) staged in LDS per ci; weights scalar-loaded.
template<int K, int COT>
__global__ void __launch_bounds__(256, 2)
convk_tiled(const float* __restrict__ in, const float* __restrict__ w,
            const float* __restrict__ bias, float* __restrict__ out,
            int CI, int OB, int co_off, int do_affine,
            const float* __restrict__ s, const float* __restrict__ o)
{
    constexpr int PAD = K / 2;
    constexpr int TH = 4;
    constexpr int LW = 64 + 2 * PAD;
    constexpr int LH = TH + 2 * PAD;
    constexpr int KK = K * K;
    __shared__ float tile[LH * LW];
    int tid = threadIdx.x;
    int h0 = blockIdx.x * TH;
    int coL = blockIdx.y * COT;
    int b = blockIdx.z;
    int r = tid >> 6, x = tid & 63;
    float acc[COT];
#pragma unroll
    for (int k = 0; k < COT; ++k) acc[k] = bias[coL + k];
    const float* inb = in + (size_t)b * CI * HW;
    for (int ci = 0; ci < CI; ++ci) {
        const float* ic = inb + (size_t)ci * HW;
        for (int i = tid; i < LH * LW; i += 256) {
            int rr = i / LW, cc = i - rr * LW;
            int gh = h0 - PAD + rr, gx = cc - PAD;
            float v = 0.f;
            if ((unsigned)gh < 64u && (unsigned)gx < 64u) v = ic[gh * 64 + gx];
            tile[i] = v;
        }
        __syncthreads();
        float xr[KK];
        const float* tp = tile + r * LW + x;
#pragma unroll
        for (int kh = 0; kh < K; ++kh)
#pragma unroll
            for (int kw = 0; kw < K; ++kw) xr[kh * K + kw] = tp[kh * LW + kw];
        const float* wci = w + (size_t)ci * KK;
#pragma unroll
        for (int k = 0; k < COT; ++k) {
            const float* wk = wci + (size_t)(coL + k) * CI * KK;
#pragma unroll
            for (int j = 0; j < KK; ++j) acc[k] += wk[j] * xr[j];
        }
        __syncthreads();
    }
    int p = (h0 + r) * 64 + x;
#pragma unroll
    for (int k = 0; k < COT; ++k) {
        float v = acc[k];
        if (do_affine) v = fmaxf(v, 0.f) * s[coL + k] + o[coL + k];
        out[((size_t)(b * OB + co_off + coL + k)) * HW + p] = v;
    }
}

// ---------------- cosine similarity over groups of 128 consecutive floats
__global__ void sim_kernel(const float* __restrict__ r1, const float* __restrict__ r2,
                           float* __restrict__ sim)
{
    int gw = blockIdx.x * 4 + (threadIdx.x >> 6);
    int lane = threadIdx.x & 63;
    int b = gw >> 12, n = gw & 4095;
    const float* p1 = r1 + (size_t)b * 524288 + (size_t)n * 128;
    const float* p2 = r2 + (size_t)b * 524288 + (size_t)n * 128;
    float a0 = p1[lane], a1 = p1[lane + 64];
    float b0 = p2[lane], b1 = p2[lane + 64];
    float dot = a0 * b0 + a1 * b1;
    float n1 = a0 * a0 + a1 * a1;
    float n2 = b0 * b0 + b1 * b1;
    for (int m = 32; m; m >>= 1) {
        dot += __shfl_xor(dot, m);
        n1  += __shfl_xor(n1, m);
        n2  += __shfl_xor(n2, m);
    }
    if (lane == 0) sim[b * 4096 + n] = dot / fmaxf(sqrtf(n1) * sqrtf(n2), 1e-8f);
}

// ---------------- x = concat(dif1, dif2) in [B][256][HW]
__global__ void x_kernel(const float* __restrict__ r1, const float* __restrict__ r2,
                         const float* __restrict__ sim, float* __restrict__ xo)
{
    size_t i = (size_t)blockIdx.x * 256 + threadIdx.x;
    int p = (int)(i & 4095);
    int cc = (int)((i >> 12) & 255);
    int b = (int)(i >> 20);
    int c = cc & 127;
    const float* R = (cc & 128) ? r2 : r1;
    const float* Rb = R + (size_t)b * 524288;
    float sv = sim[b * 4096 + p];
    xo[i] = Rb[(size_t)p * 128 + c] * (1.f - sv) + Rb[(size_t)c * 4096 + p];
}

// ---------------- simp = avgpool2(|sim1 - sim2|) in [B][128][32][32]
__global__ void simp_kernel(const float* __restrict__ r1, const float* __restrict__ r2,
                            const float* __restrict__ sim, float* __restrict__ simp)
{
    int i = blockIdx.x * 256 + threadIdx.x;
    int w2 = i & 31, h2 = (i >> 5) & 31, c = (i >> 10) & 127, b = i >> 17;
    const float* R1 = r1 + (size_t)b * 524288;
    const float* R2 = r2 + (size_t)b * 524288;
    const float* sb = sim + b * 4096;
    float acc = 0.f;
    for (int dh = 0; dh < 2; ++dh)
        for (int dw = 0; dw < 2; ++dw) {
            int p = (2 * h2 + dh) * 64 + (2 * w2 + dw);
            float d = (R1[(size_t)p * 128 + c] - R2[(size_t)p * 128 + c]) * sb[p]
                    + (R1[(size_t)c * 4096 + p] - R2[(size_t)c * 4096 + p]);
            acc += fabsf(d);
        }
    simp[i] = acc * 0.25f;
}

// ---------------- GEMM1: S[n,m] = sum_c attn[n,c]*inc[c,m]; 16 n per thread
__global__ void __launch_bounds__(256, 2)
attn_gemm1_t(const float* __restrict__ attn, const float* __restrict__ inc,
             float* __restrict__ S)
{
    int m = blockIdx.x * 256 + threadIdx.x;
    int n0 = blockIdx.y * 16;
    float acc[16] = {};
#pragma unroll 4
    for (int c = 0; c < 128; ++c) {
        float v = inc[(size_t)c * HW + m];
#pragma unroll
        for (int k = 0; k < 16; ++k) acc[k] += attn[(n0 + k) * 128 + c] * v;
    }
#pragma unroll
    for (int k = 0; k < 16; ++k) S[(size_t)(n0 + k) * HW + m] = acc[k];
}

// ---------------- per-row exp(x - max), keep unnormalized; rs = 1/rowsum
__global__ void softmax_exp(float* __restrict__ S, float* __restrict__ rs)
{
    __shared__ float red[256];
    float* row = S + (size_t)blockIdx.x * HW;
    int t = threadIdx.x;
    float mx = -1e30f;
    for (int i = t; i < HW; i += 256) mx = fmaxf(mx, row[i]);
    red[t] = mx; __syncthreads();
    for (int s2 = 128; s2; s2 >>= 1) { if (t < s2) red[t] = fmaxf(red[t], red[t + s2]); __syncthreads(); }
    mx = red[0]; __syncthreads();
    float sum = 0.f;
    for (int i = t; i < HW; i += 256) { float e = __expf(row[i] - mx); row[i] = e; sum += e; }
    red[t] = sum; __syncthreads();
    for (int s2 = 128; s2; s2 >>= 1) { if (t < s2) red[t] += red[t + s2]; __syncthreads(); }
    if (t == 0) rs[blockIdx.x] = 1.f / red[0];
}

// ---------------- GEMM2: out[c,m] = sum_n attn[n,c]*(P[n,m]*rs[n]) + inc[c,m]
__global__ void __launch_bounds__(256, 2)
attn_gemm2_t(const float* __restrict__ attn, const float* __restrict__ P,
             const float* __restrict__ rs, const float* __restrict__ inc,
             float* __restrict__ outp)
{
    int m = blockIdx.x * 256 + threadIdx.x;
    int c0 = blockIdx.y * 8;
    float acc[8] = {};
#pragma unroll 4
    for (int n = 0; n < 1024; ++n) {
        float pv = P[(size_t)n * HW + m] * rs[n];
#pragma unroll
        for (int k = 0; k < 8; ++k) acc[k] += attn[n * 128 + c0 + k] * pv;
    }
#pragma unroll
    for (int k = 0; k < 8; ++k)
        outp[(size_t)(c0 + k) * HW + m] = acc[k] + inc[(size_t)(c0 + k) * HW + m];
}

// ---------------- bilinear 2x upsample, half-pixel centers, edge clamp
__global__ void upsample_kernel(const float* __restrict__ in, float* __restrict__ out)
{
    int i = blockIdx.x * 256 + threadIdx.x;
    int x = i & 127, y = (i >> 7) & 127, bc = i >> 14;
    const float* ib = in + (size_t)bc * HW;
    float sy = 0.5f * y - 0.25f;
    float sx = 0.5f * x - 0.25f;
    int y0 = (int)floorf(sy); float ty = sy - y0;
    int x0 = (int)floorf(sx); float tx = sx - x0;
    int y0c = min(max(y0, 0), 63), y1c = min(max(y0 + 1, 0), 63);
    int x0c = min(max(x0, 0), 63), x1c = min(max(x0 + 1, 0), 63);
    float v00 = ib[y0c * 64 + x0c], v01 = ib[y0c * 64 + x1c];
    float v10 = ib[y1c * 64 + x0c], v11 = ib[y1c * 64 + x1c];
    out[i] = (1.f - ty) * ((1.f - tx) * v00 + tx * v01) + ty * ((1.f - tx) * v10 + tx * v11);
}

extern "C" void kernel_launch(void* const* d_in, const int* in_sizes, int n_in,
                              void* d_out, int out_size, void* d_ws, size_t ws_size,
                              hipStream_t stream)
{
    const float* t1       = (const float*)d_in[0];
    const float* t2       = (const float*)d_in[1];
    const float* t1_w     = (const float*)d_in[2];
    const float* t1_b     = (const float*)d_in[3];
    const float* t2_w     = (const float*)d_in[4];
    const float* t2_b     = (const float*)d_in[5];
    const float* df_res_w = (const float*)d_in[6];
    const float* df_res_b = (const float*)d_in[7];
    const float* df_res_s = (const float*)d_in[8];
    const float* df_res_o = (const float*)d_in[9];
    const float* df_b0_w  = (const float*)d_in[10];
    const float* df_b0_b  = (const float*)d_in[11];
    const float* df_b0_s  = (const float*)d_in[12];
    const float* df_b0_o  = (const float*)d_in[13];
    const float* df_b1_w  = (const float*)d_in[14];
    const float* df_b1_b  = (const float*)d_in[15];
    const float* df_b1_s  = (const float*)d_in[16];
    const float* df_b1_o  = (const float*)d_in[17];
    const float* df_fu_w  = (const float*)d_in[18];
    const float* df_fu_b  = (const float*)d_in[19];
    const float* df_fu_s  = (const float*)d_in[20];
    const float* df_fu_o  = (const float*)d_in[21];
    const float* br1_w    = (const float*)d_in[22];
    const float* br1_b    = (const float*)d_in[23];
    const float* br2_w    = (const float*)d_in[24];
    const float* br2_b    = (const float*)d_in[25];
    const float* fu_w     = (const float*)d_in[26];
    const float* fu_b     = (const float*)d_in[27];
    const float* fu_s     = (const float*)d_in[28];
    const float* fu_o     = (const float*)d_in[29];

    float* ws = (float*)d_ws;
    float* res1 = ws;                   // 2,097,152  -> later r -> later inc1
    float* res2 = ws + 2097152;         // 2,097,152  -> later b01 -> later inc2
    float* xbuf = ws + 4194304;         // 4,194,304  (x; later dif, fused at +2M)
    float* Sbuf = ws + 8388608;         // 4,194,304  scores scratch per (b,branch)
    float* abuf = ws + 12582912;        // 4,194,304  concat(a1,a2) [B][256][HW]
    float* simp = ws + 16777216;        // 524,288
    float* simv = ws + 17301504;        // 16,384
    float* rsb  = ws + 17317888;        // 1,024

    dim3 blk(256);

    // res1/res2 = 1x1 conv(t1/t2)
    conv1x1_tiled<16><<<dim3(16, 8, 4), blk, 0, stream>>>(t1, t1_w, t1_b, res1, 256, 128, 0, nullptr, nullptr, nullptr);
    conv1x1_tiled<16><<<dim3(16, 8, 4), blk, 0, stream>>>(t2, t2_w, t2_b, res2, 256, 128, 0, nullptr, nullptr, nullptr);
    // cosine sim over flat groups of 128
    sim_kernel<<<4096, blk, 0, stream>>>(res1, res2, simv);
    // x = concat(dif1,dif2); simp = avgpool2(|sim1-sim2|)
    x_kernel<<<16384, blk, 0, stream>>>(res1, res2, simv, xbuf);
    simp_kernel<<<2048, blk, 0, stream>>>(res1, res2, simv, simp);
    // r = stdconv1x1(x)  -> res1 slot
    conv1x1_tiled<16><<<dim3(16, 8, 4), blk, 0, stream>>>(xbuf, df_res_w, df_res_b, res1, 256, 128, 1, df_res_s, df_res_o, nullptr);
    // b0 (3x3) -> res2 ch0..63 ; b1 (5x5) -> res2 ch64..127
    convk_tiled<3, 8><<<dim3(16, 8, 4), blk, 0, stream>>>(res1, df_b0_w, df_b0_b, res2, 128, 128, 0, 1, df_b0_s, df_b0_o);
    convk_tiled<5, 8><<<dim3(16, 8, 4), blk, 0, stream>>>(res1, df_b1_w, df_b1_b, res2, 128, 128, 64, 1, df_b1_s, df_b1_o);
    // dif = stdconv1x1(b01) + r   -> xbuf (x dead)
    conv1x1_tiled<16><<<dim3(16, 8, 4), blk, 0, stream>>>(res2, df_fu_w, df_fu_b, xbuf, 128, 128, 1, df_fu_s, df_fu_o, res1);
    // inc1 = conv3x3(dif) -> res1 ; inc2 = conv5x5(dif) -> res2
    convk_tiled<3, 16><<<dim3(16, 8, 4), blk, 0, stream>>>(xbuf, br1_w, br1_b, res1, 128, 128, 0, 0, nullptr, nullptr);
    convk_tiled<5, 16><<<dim3(16, 8, 4), blk, 0, stream>>>(xbuf, br2_w, br2_b, res2, 128, 128, 0, 0, nullptr, nullptr);
    // dual-branch attention
    for (int br = 0; br < 2; ++br) {
        const float* incb = br ? res2 : res1;
        for (int b = 0; b < 4; ++b) {
            const float* at = simp + (size_t)b * 131072;
            const float* ib = incb + (size_t)b * 524288;
            attn_gemm1_t<<<dim3(16, 64), blk, 0, stream>>>(at, ib, Sbuf);
            softmax_exp<<<1024, blk, 0, stream>>>(Sbuf, rsb);
            attn_gemm2_t<<<dim3(16, 16), blk, 0, stream>>>(at, Sbuf, rsb, ib,
                abuf + ((size_t)b * 256 + (size_t)br * 128) * 4096);
        }
    }
    // fused = stdconv1x1(concat(a1,a2)) + dif
    float* dif = xbuf;
    float* fused = xbuf + 2097152;
    conv1x1_tiled<16><<<dim3(16, 8, 4), blk, 0, stream>>>(abuf, fu_w, fu_b, fused, 256, 128, 1, fu_s, fu_o, dif);
    // bilinear 2x upsample -> d_out
    upsample_kernel<<<32768, blk, 0, stream>>>(fused, (float*)d_out);
}

// Round 3
// 1793.694 us; speedup vs baseline: 3.5301x; 1.7208x over previous
//
#include <hip/hip_runtime.h>
#include <math.h>

#define HW 4096   // 64*64

typedef __attribute__((ext_vector_type(8))) short short8;
typedef __attribute__((ext_vector_type(4))) float floatx4;

__device__ inline unsigned short f2bf(float f) {
    unsigned int u = __float_as_uint(f);
    unsigned int r = (u + 0x7fffu + ((u >> 16) & 1u)) >> 16;
    return (unsigned short)r;
}

// ---------------- zero scratch (uint4 stores)
__global__ void zero_kernel(uint4* __restrict__ p, int n)
{
    int i = blockIdx.x * 256 + threadIdx.x;
    if (i < n) p[i] = make_uint4(0u, 0u, 0u, 0u);
}

// ---------------- weight prepack: W[CO][CI][K][K] fp32 -> Wp[kh][kw][co][ci] bf16
__global__ void prepack_w(const float* __restrict__ w, unsigned short* __restrict__ wp,
                          int CO, int CI, int KK)
{
    int i = blockIdx.x * 256 + threadIdx.x;
    if (i >= CO * CI * KK) return;
    int ci = i % CI;
    int t = i / CI;
    int co = t % CO;
    int kk = t / CO;
    wp[i] = f2bf(w[(co * CI + ci) * KK + kk]);
}

// ---------------- 1x1 conv, register-blocked; optional bf16 pixel-major padded copy (xt)
__global__ void __launch_bounds__(256, 2)
conv1x1_tiled(const float* __restrict__ in, const float* __restrict__ w,
              const float* __restrict__ bias, float* __restrict__ out,
              int CI, int CO, int do_affine,
              const float* __restrict__ s, const float* __restrict__ o,
              const float* __restrict__ addbuf, unsigned short* __restrict__ xt)
{
    int m = blockIdx.x * 256 + threadIdx.x;
    int c0 = blockIdx.y * 16;
    int b = blockIdx.z;
    float acc[16];
#pragma unroll
    for (int k = 0; k < 16; ++k) acc[k] = bias[c0 + k];
    const float* inb = in + (size_t)b * CI * HW + m;
#pragma unroll 4
    for (int ci = 0; ci < CI; ++ci) {
        float v = inb[(size_t)ci * HW];
#pragma unroll
        for (int k = 0; k < 16; ++k) acc[k] += w[(c0 + k) * CI + ci] * v;
    }
    float vv[16];
#pragma unroll
    for (int k = 0; k < 16; ++k) {
        float v = acc[k];
        if (do_affine) v = fmaxf(v, 0.f) * s[c0 + k] + o[c0 + k];
        size_t oidx = ((size_t)(b * CO + c0 + k)) * HW + m;
        if (addbuf) v += addbuf[oidx];
        out[oidx] = v;
        vv[k] = v;
    }
    if (xt) {
        union { unsigned short u16[16]; uint4 q[2]; } pk;
#pragma unroll
        for (int k = 0; k < 16; ++k) pk.u16[k] = f2bf(vv[k]);
        int h = m >> 6, wc = m & 63;
        unsigned short* xp = xt + ((size_t)b * 68 * 68 + (h + 2) * 68 + (wc + 2)) * 128 + c0;
        *(uint4*)xp = pk.q[0];
        *((uint4*)xp + 1) = pk.q[1];
    }
}

// ---------------- KxK conv as implicit-GEMM bf16 MFMA.
// xt: [b][68][68][128] bf16, zero-padded borders (2 each side).
// wp: [kh][kw][CO][128] bf16.  Block = 1 image row x CO cols; wave owns 16*NB co.
template<int K, int CO, int NB>
__global__ void __launch_bounds__(256)
convk_mfma(const unsigned short* __restrict__ xt, const unsigned short* __restrict__ wp,
           const float* __restrict__ bias, float* __restrict__ out,
           int OB, int co_off, int do_affine,
           const float* __restrict__ s, const float* __restrict__ o)
{
    constexpr int CI = 128;
    constexpr int PAD = K / 2;
    constexpr int RO = 2 - PAD;     // storage pad (2) minus conv pad
    int tid = threadIdx.x;
    int wave = tid >> 6, lane = tid & 63;
    int h = blockIdx.x, b = blockIdx.y;
    int co0 = wave * 16 * NB;
    int n = lane & 15, q = lane >> 4;
    floatx4 acc[4][NB];
#pragma unroll
    for (int mt = 0; mt < 4; ++mt)
#pragma unroll
        for (int nt = 0; nt < NB; ++nt) acc[mt][nt] = (floatx4){0.f, 0.f, 0.f, 0.f};

    const unsigned short* xb = xt + (size_t)b * (68 * 68 * 128) + 8 * q;
    for (int ci0 = 0; ci0 < CI; ci0 += 32) {
#pragma unroll
        for (int kh = 0; kh < K; ++kh) {
            const unsigned short* xrow = xb + (size_t)(((h + kh + RO) * 68 + RO) * 128 + ci0);
            const unsigned short* wrow = wp + (size_t)(kh * K * CO * CI) + ci0 + 8 * q;
#pragma unroll
            for (int kw = 0; kw < K; ++kw) {
                short8 bfr[NB];
#pragma unroll
                for (int nt = 0; nt < NB; ++nt)
                    bfr[nt] = *(const short8*)(wrow + (size_t)((kw * CO + co0 + nt * 16 + n) * CI));
#pragma unroll
                for (int mt = 0; mt < 4; ++mt) {
                    short8 afr = *(const short8*)(xrow + (mt * 16 + n + kw) * 128);
#pragma unroll
                    for (int nt = 0; nt < NB; ++nt)
                        acc[mt][nt] = __builtin_amdgcn_mfma_f32_16x16x32_bf16(afr, bfr[nt], acc[mt][nt], 0, 0, 0);
                }
            }
        }
    }
    int px0 = h * 64 + q * 4;
#pragma unroll
    for (int nt = 0; nt < NB; ++nt) {
        int co = co0 + nt * 16 + n;
        float bi = bias[co];
        float sc = do_affine ? s[co] : 1.f;
        float of = do_affine ? o[co] : 0.f;
        float* ob = out + ((size_t)(b * OB + co_off + co)) * HW;
#pragma unroll
        for (int mt = 0; mt < 4; ++mt)
#pragma unroll
            for (int r = 0; r < 4; ++r) {
                float v = acc[mt][nt][r] + bi;
                if (do_affine) v = fmaxf(v, 0.f) * sc + of;
                ob[px0 + mt * 16 + r] = v;
            }
    }
}

// ---------------- cosine similarity over groups of 128 consecutive floats
__global__ void sim_kernel(const float* __restrict__ r1, const float* __restrict__ r2,
                           float* __restrict__ sim)
{
    int gw = blockIdx.x * 4 + (threadIdx.x >> 6);
    int lane = threadIdx.x & 63;
    int b = gw >> 12, n = gw & 4095;
    const float* p1 = r1 + (size_t)b * 524288 + (size_t)n * 128;
    const float* p2 = r2 + (size_t)b * 524288 + (size_t)n * 128;
    float a0 = p1[lane], a1 = p1[lane + 64];
    float b0 = p2[lane], b1 = p2[lane + 64];
    float dot = a0 * b0 + a1 * b1;
    float n1 = a0 * a0 + a1 * a1;
    float n2 = b0 * b0 + b1 * b1;
    for (int m = 32; m; m >>= 1) {
        dot += __shfl_xor(dot, m);
        n1  += __shfl_xor(n1, m);
        n2  += __shfl_xor(n2, m);
    }
    if (lane == 0) sim[b * 4096 + n] = dot / fmaxf(sqrtf(n1) * sqrtf(n2), 1e-8f);
}

// ---------------- x = concat(dif1, dif2) in [B][256][HW]
__global__ void x_kernel(const float* __restrict__ r1, const float* __restrict__ r2,
                         const float* __restrict__ sim, float* __restrict__ xo)
{
    size_t i = (size_t)blockIdx.x * 256 + threadIdx.x;
    int p = (int)(i & 4095);
    int cc = (int)((i >> 12) & 255);
    int b = (int)(i >> 20);
    int c = cc & 127;
    const float* R = (cc & 128) ? r2 : r1;
    const float* Rb = R + (size_t)b * 524288;
    float sv = sim[b * 4096 + p];
    xo[i] = Rb[(size_t)p * 128 + c] * (1.f - sv) + Rb[(size_t)c * 4096 + p];
}

// ---------------- simp = avgpool2(|sim1 - sim2|) in [B][128][32][32]
__global__ void simp_kernel(const float* __restrict__ r1, const float* __restrict__ r2,
                            const float* __restrict__ sim, float* __restrict__ simp)
{
    int i = blockIdx.x * 256 + threadIdx.x;
    int w2 = i & 31, h2 = (i >> 5) & 31, c = (i >> 10) & 127, b = i >> 17;
    const float* R1 = r1 + (size_t)b * 524288;
    const float* R2 = r2 + (size_t)b * 524288;
    const float* sb = sim + b * 4096;
    float acc = 0.f;
    for (int dh = 0; dh < 2; ++dh)
        for (int dw = 0; dw < 2; ++dw) {
            int p = (2 * h2 + dh) * 64 + (2 * w2 + dw);
            float d = (R1[(size_t)p * 128 + c] - R2[(size_t)p * 128 + c]) * sb[p]
                    + (R1[(size_t)c * 4096 + p] - R2[(size_t)c * 4096 + p]);
            acc += fabsf(d);
        }
    simp[i] = acc * 0.25f;
}

// ---------------- GEMM1: S[n,m] = sum_c attn[n,c]*inc[c,m]; 16 n per thread
__global__ void __launch_bounds__(256, 2)
attn_gemm1_t(const float* __restrict__ attn, const float* __restrict__ inc,
             float* __restrict__ S)
{
    int m = blockIdx.x * 256 + threadIdx.x;
    int n0 = blockIdx.y * 16;
    float acc[16] = {};
#pragma unroll 4
    for (int c = 0; c < 128; ++c) {
        float v = inc[(size_t)c * HW + m];
#pragma unroll
        for (int k = 0; k < 16; ++k) acc[k] += attn[(n0 + k) * 128 + c] * v;
    }
#pragma unroll
    for (int k = 0; k < 16; ++k) S[(size_t)(n0 + k) * HW + m] = acc[k];
}

// ---------------- per-row exp(x - max), keep unnormalized; rs = 1/rowsum
__global__ void softmax_exp(float* __restrict__ S, float* __restrict__ rs)
{
    __shared__ float red[256];
    float* row = S + (size_t)blockIdx.x * HW;
    int t = threadIdx.x;
    float mx = -1e30f;
    for (int i = t; i < HW; i += 256) mx = fmaxf(mx, row[i]);
    red[t] = mx; __syncthreads();
    for (int s2 = 128; s2; s2 >>= 1) { if (t < s2) red[t] = fmaxf(red[t], red[t + s2]); __syncthreads(); }
    mx = red[0]; __syncthreads();
    float sum = 0.f;
    for (int i = t; i < HW; i += 256) { float e = __expf(row[i] - mx); row[i] = e; sum += e; }
    red[t] = sum; __syncthreads();
    for (int s2 = 128; s2; s2 >>= 1) { if (t < s2) red[t] += red[t + s2]; __syncthreads(); }
    if (t == 0) rs[blockIdx.x] = 1.f / red[0];
}

// ---------------- GEMM2: out[c,m] = sum_n attn[n,c]*(P[n,m]*rs[n]) + inc[c,m]
__global__ void __launch_bounds__(256, 2)
attn_gemm2_t(const float* __restrict__ attn, const float* __restrict__ P,
             const float* __restrict__ rs, const float* __restrict__ inc,
             float* __restrict__ outp)
{
    int m = blockIdx.x * 256 + threadIdx.x;
    int c0 = blockIdx.y * 8;
    float acc[8] = {};
#pragma unroll 4
    for (int n = 0; n < 1024; ++n) {
        float pv = P[(size_t)n * HW + m] * rs[n];
#pragma unroll
        for (int k = 0; k < 8; ++k) acc[k] += attn[n * 128 + c0 + k] * pv;
    }
#pragma unroll
    for (int k = 0; k < 8; ++k)
        outp[(size_t)(c0 + k) * HW + m] = acc[k] + inc[(size_t)(c0 + k) * HW + m];
}

// ---------------- bilinear 2x upsample, half-pixel centers, edge clamp
__global__ void upsample_kernel(const float* __restrict__ in, float* __restrict__ out)
{
    int i = blockIdx.x * 256 + threadIdx.x;
    int x = i & 127, y = (i >> 7) & 127, bc = i >> 14;
    const float* ib = in + (size_t)bc * HW;
    float sy = 0.5f * y - 0.25f;
    float sx = 0.5f * x - 0.25f;
    int y0 = (int)floorf(sy); float ty = sy - y0;
    int x0 = (int)floorf(sx); float tx = sx - x0;
    int y0c = min(max(y0, 0), 63), y1c = min(max(y0 + 1, 0), 63);
    int x0c = min(max(x0, 0), 63), x1c = min(max(x0 + 1, 0), 63);
    float v00 = ib[y0c * 64 + x0c], v01 = ib[y0c * 64 + x1c];
    float v10 = ib[y1c * 64 + x0c], v11 = ib[y1c * 64 + x1c];
    out[i] = (1.f - ty) * ((1.f - tx) * v00 + tx * v01) + ty * ((1.f - tx) * v10 + tx * v11);
}

extern "C" void kernel_launch(void* const* d_in, const int* in_sizes, int n_in,
                              void* d_out, int out_size, void* d_ws, size_t ws_size,
                              hipStream_t stream)
{
    const float* t1       = (const float*)d_in[0];
    const float* t2       = (const float*)d_in[1];
    const float* t1_w     = (const float*)d_in[2];
    const float* t1_b     = (const float*)d_in[3];
    const float* t2_w     = (const float*)d_in[4];
    const float* t2_b     = (const float*)d_in[5];
    const float* df_res_w = (const float*)d_in[6];
    const float* df_res_b = (const float*)d_in[7];
    const float* df_res_s = (const float*)d_in[8];
    const float* df_res_o = (const float*)d_in[9];
    const float* df_b0_w  = (const float*)d_in[10];
    const float* df_b0_b  = (const float*)d_in[11];
    const float* df_b0_s  = (const float*)d_in[12];
    const float* df_b0_o  = (const float*)d_in[13];
    const float* df_b1_w  = (const float*)d_in[14];
    const float* df_b1_b  = (const float*)d_in[15];
    const float* df_b1_s  = (const float*)d_in[16];
    const float* df_b1_o  = (const float*)d_in[17];
    const float* df_fu_w  = (const float*)d_in[18];
    const float* df_fu_b  = (const float*)d_in[19];
    const float* df_fu_s  = (const float*)d_in[20];
    const float* df_fu_o  = (const float*)d_in[21];
    const float* br1_w    = (const float*)d_in[22];
    const float* br1_b    = (const float*)d_in[23];
    const float* br2_w    = (const float*)d_in[24];
    const float* br2_b    = (const float*)d_in[25];
    const float* fu_w     = (const float*)d_in[26];
    const float* fu_b     = (const float*)d_in[27];
    const float* fu_s     = (const float*)d_in[28];
    const float* fu_o     = (const float*)d_in[29];

    float* ws = (float*)d_ws;
    float* res1 = ws;                   // 2,097,152 f  (res1 -> r -> inc1)
    float* res2 = ws + 2097152;         // 2,097,152 f  (res2 -> b01 -> inc2)
    float* xbuf = ws + 4194304;         // 4,194,304 f  (x -> dif; fused at +2M)
    float* Sbuf = ws + 8388608;         // 4,194,304 f  scores (attention phase)
    float* abuf = ws + 12582912;        // 4,194,304 f  concat(a1,a2)
    float* simp = ws + 16777216;        // 524,288 f
    float* simv = ws + 17301504;        // 16,384 f
    float* rsb  = ws + 17317888;        // 1,024 f

    // bf16 scratch overlays the Sbuf region (dead until attention phase)
    unsigned short* us     = (unsigned short*)Sbuf;
    unsigned short* xt_r   = us;                 // 68*68*128*4 = 2,367,488 u16
    unsigned short* xt_dif = us + 2367488;       // 2,367,488 u16
    unsigned short* wp_b0  = us + 4800000;       // 73,728
    unsigned short* wp_b1  = us + 4880000;       // 204,800
    unsigned short* wp_br1 = us + 5100000;       // 147,456
    unsigned short* wp_br2 = us + 5260000;       // 409,600  (ends < 8,388,608)

    dim3 blk(256);

    // zero padded bf16 inputs; prepack conv weights (all independent)
    zero_kernel<<<2312, blk, 0, stream>>>((uint4*)us, 591872);
    prepack_w<<<288,  blk, 0, stream>>>(df_b0_w, wp_b0, 64, 128, 9);
    prepack_w<<<800,  blk, 0, stream>>>(df_b1_w, wp_b1, 64, 128, 25);
    prepack_w<<<576,  blk, 0, stream>>>(br1_w, wp_br1, 128, 128, 9);
    prepack_w<<<1600, blk, 0, stream>>>(br2_w, wp_br2, 128, 128, 25);

    // res1/res2 = 1x1 conv(t1/t2)
    conv1x1_tiled<<<dim3(16, 8, 4), blk, 0, stream>>>(t1, t1_w, t1_b, res1, 256, 128, 0, nullptr, nullptr, nullptr, nullptr);
    conv1x1_tiled<<<dim3(16, 8, 4), blk, 0, stream>>>(t2, t2_w, t2_b, res2, 256, 128, 0, nullptr, nullptr, nullptr, nullptr);
    sim_kernel<<<4096, blk, 0, stream>>>(res1, res2, simv);
    x_kernel<<<16384, blk, 0, stream>>>(res1, res2, simv, xbuf);
    simp_kernel<<<2048, blk, 0, stream>>>(res1, res2, simv, simp);
    // r = stdconv1x1(x) -> res1 (+ bf16 padded copy)
    conv1x1_tiled<<<dim3(16, 8, 4), blk, 0, stream>>>(xbuf, df_res_w, df_res_b, res1, 256, 128, 1, df_res_s, df_res_o, nullptr, xt_r);
    // b0 3x3 -> res2[0:64], b1 5x5 -> res2[64:128]  (MFMA)
    convk_mfma<3, 64, 1><<<dim3(64, 4), blk, 0, stream>>>(xt_r, wp_b0, df_b0_b, res2, 128, 0, 1, df_b0_s, df_b0_o);
    convk_mfma<5, 64, 1><<<dim3(64, 4), blk, 0, stream>>>(xt_r, wp_b1, df_b1_b, res2, 128, 64, 1, df_b1_s, df_b1_o);
    // dif = stdconv1x1(b01) + r -> xbuf (+ bf16 padded copy)
    conv1x1_tiled<<<dim3(16, 8, 4), blk, 0, stream>>>(res2, df_fu_w, df_fu_b, xbuf, 128, 128, 1, df_fu_s, df_fu_o, res1, xt_dif);
    // inc1 = conv3x3(dif) -> res1 ; inc2 = conv5x5(dif) -> res2  (MFMA)
    convk_mfma<3, 128, 2><<<dim3(64, 4), blk, 0, stream>>>(xt_dif, wp_br1, br1_b, res1, 128, 0, 0, nullptr, nullptr);
    convk_mfma<5, 128, 2><<<dim3(64, 4), blk, 0, stream>>>(xt_dif, wp_br2, br2_b, res2, 128, 0, 0, nullptr, nullptr);
    // dual-branch attention (fp32; xt/wp scratch now dead, Sbuf free)
    for (int br = 0; br < 2; ++br) {
        const float* incb = br ? res2 : res1;
        for (int b = 0; b < 4; ++b) {
            const float* at = simp + (size_t)b * 131072;
            const float* ib = incb + (size_t)b * 524288;
            attn_gemm1_t<<<dim3(16, 64), blk, 0, stream>>>(at, ib, Sbuf);
            softmax_exp<<<1024, blk, 0, stream>>>(Sbuf, rsb);
            attn_gemm2_t<<<dim3(16, 16), blk, 0, stream>>>(at, Sbuf, rsb, ib,
                abuf + ((size_t)b * 256 + (size_t)br * 128) * 4096);
        }
    }
    // fused = stdconv1x1(concat(a1,a2)) + dif
    float* dif = xbuf;
    float* fused = xbuf + 2097152;
    conv1x1_tiled<<<dim3(16, 8, 4), blk, 0, stream>>>(abuf, fu_w, fu_b, fused, 256, 128, 1, fu_s, fu_o, dif, nullptr);
    // bilinear 2x upsample -> d_out
    upsample_kernel<<<32768, blk, 0, stream>>>(fused, (float*)d_out);
}

// Round 4
// 865.455 us; speedup vs baseline: 7.3162x; 2.0725x over previous
//
#include <hip/hip_runtime.h>
#include <math.h>

#define HW 4096   // 64*64

typedef __attribute__((ext_vector_type(8))) short short8;
typedef __attribute__((ext_vector_type(4))) float floatx4;

__device__ inline unsigned short f2bf(float f) {
    unsigned int u = __float_as_uint(f);
    unsigned int r = (u + 0x7fffu + ((u >> 16) & 1u)) >> 16;
    return (unsigned short)r;
}
__device__ inline float bf2f(unsigned short u) {
    return __uint_as_float(((unsigned int)u) << 16);
}

// ---------------- zero scratch (uint4 stores)
__global__ void zero_kernel(uint4* __restrict__ p, int n)
{
    int i = blockIdx.x * 256 + threadIdx.x;
    if (i < n) p[i] = make_uint4(0u, 0u, 0u, 0u);
}

// ---------------- weight prepack: W[CO][CI][K][K] fp32 -> Wp[kh][kw][co][ci] bf16
__global__ void prepack_w(const float* __restrict__ w, unsigned short* __restrict__ wp,
                          int CO, int CI, int KK)
{
    int i = blockIdx.x * 256 + threadIdx.x;
    if (i >= CO * CI * KK) return;
    int ci = i % CI;
    int t = i / CI;
    int co = t % CO;
    int kk = t / CO;
    wp[i] = f2bf(w[(co * CI + ci) * KK + kk]);
}

// ---------------- 1x1 conv, register-blocked; optional bf16 pixel-major padded copy (xt)
__global__ void __launch_bounds__(256, 2)
conv1x1_tiled(const float* __restrict__ in, const float* __restrict__ w,
              const float* __restrict__ bias, float* __restrict__ out,
              int CI, int CO, int do_affine,
              const float* __restrict__ s, const float* __restrict__ o,
              const float* __restrict__ addbuf, unsigned short* __restrict__ xt)
{
    int m = blockIdx.x * 256 + threadIdx.x;
    int c0 = blockIdx.y * 16;
    int b = blockIdx.z;
    float acc[16];
#pragma unroll
    for (int k = 0; k < 16; ++k) acc[k] = bias[c0 + k];
    const float* inb = in + (size_t)b * CI * HW + m;
#pragma unroll 4
    for (int ci = 0; ci < CI; ++ci) {
        float v = inb[(size_t)ci * HW];
#pragma unroll
        for (int k = 0; k < 16; ++k) acc[k] += w[(c0 + k) * CI + ci] * v;
    }
    float vv[16];
#pragma unroll
    for (int k = 0; k < 16; ++k) {
        float v = acc[k];
        if (do_affine) v = fmaxf(v, 0.f) * s[c0 + k] + o[c0 + k];
        size_t oidx = ((size_t)(b * CO + c0 + k)) * HW + m;
        if (addbuf) v += addbuf[oidx];
        out[oidx] = v;
        vv[k] = v;
    }
    if (xt) {
        union { unsigned short u16[16]; uint4 q[2]; } pk;
#pragma unroll
        for (int k = 0; k < 16; ++k) pk.u16[k] = f2bf(vv[k]);
        int h = m >> 6, wc = m & 63;
        unsigned short* xp = xt + ((size_t)b * 68 * 68 + (h + 2) * 68 + (wc + 2)) * 128 + c0;
        *(uint4*)xp = pk.q[0];
        *((uint4*)xp + 1) = pk.q[1];
    }
}

// ---------------- KxK conv as implicit-GEMM bf16 MFMA.
// xt: [b][68][68][128] bf16 zero-padded; wp: [kh][kw][CO][128] bf16.
// Optional incT output: [b][4096 px][128 co] bf16 (attention B-operand layout).
template<int K, int CO, int NB>
__global__ void __launch_bounds__(256)
convk_mfma(const unsigned short* __restrict__ xt, const unsigned short* __restrict__ wp,
           const float* __restrict__ bias, float* __restrict__ out,
           int OB, int co_off, int do_affine,
           const float* __restrict__ s, const float* __restrict__ o,
           unsigned short* __restrict__ incT)
{
    constexpr int CI = 128;
    constexpr int PAD = K / 2;
    constexpr int RO = 2 - PAD;
    int tid = threadIdx.x;
    int wave = tid >> 6, lane = tid & 63;
    int h = blockIdx.x, b = blockIdx.y;
    int co0 = wave * 16 * NB;
    int n = lane & 15, q = lane >> 4;
    floatx4 acc[4][NB];
#pragma unroll
    for (int mt = 0; mt < 4; ++mt)
#pragma unroll
        for (int nt = 0; nt < NB; ++nt) acc[mt][nt] = (floatx4){0.f, 0.f, 0.f, 0.f};

    const unsigned short* xb = xt + (size_t)b * (68 * 68 * 128) + 8 * q;
    for (int ci0 = 0; ci0 < CI; ci0 += 32) {
#pragma unroll
        for (int kh = 0; kh < K; ++kh) {
            const unsigned short* xrow = xb + (size_t)(((h + kh + RO) * 68 + RO) * 128 + ci0);
            const unsigned short* wrow = wp + (size_t)(kh * K * CO * CI) + ci0 + 8 * q;
#pragma unroll
            for (int kw = 0; kw < K; ++kw) {
                short8 bfr[NB];
#pragma unroll
                for (int nt = 0; nt < NB; ++nt)
                    bfr[nt] = *(const short8*)(wrow + (size_t)((kw * CO + co0 + nt * 16 + n) * CI));
#pragma unroll
                for (int mt = 0; mt < 4; ++mt) {
                    short8 afr = *(const short8*)(xrow + (mt * 16 + n + kw) * 128);
#pragma unroll
                    for (int nt = 0; nt < NB; ++nt)
                        acc[mt][nt] = __builtin_amdgcn_mfma_f32_16x16x32_bf16(afr, bfr[nt], acc[mt][nt], 0, 0, 0);
                }
            }
        }
    }
    int px0 = h * 64 + q * 4;
#pragma unroll
    for (int nt = 0; nt < NB; ++nt) {
        int co = co0 + nt * 16 + n;
        float bi = bias[co];
        float sc = do_affine ? s[co] : 1.f;
        float of = do_affine ? o[co] : 0.f;
        float* ob = out + ((size_t)(b * OB + co_off + co)) * HW;
        unsigned short* tb = incT ? incT + (size_t)b * (4096 * 128) + co : nullptr;
#pragma unroll
        for (int mt = 0; mt < 4; ++mt)
#pragma unroll
            for (int r = 0; r < 4; ++r) {
                int px = px0 + mt * 16 + r;
                float v = acc[mt][nt][r] + bi;
                if (do_affine) v = fmaxf(v, 0.f) * sc + of;
                ob[px] = v;
                if (incT) tb[(size_t)px * 128] = f2bf(v);
            }
    }
}

// ---------------- cosine similarity over groups of 128 consecutive floats
__global__ void sim_kernel(const float* __restrict__ r1, const float* __restrict__ r2,
                           float* __restrict__ sim)
{
    int gw = blockIdx.x * 4 + (threadIdx.x >> 6);
    int lane = threadIdx.x & 63;
    int b = gw >> 12, n = gw & 4095;
    const float* p1 = r1 + (size_t)b * 524288 + (size_t)n * 128;
    const float* p2 = r2 + (size_t)b * 524288 + (size_t)n * 128;
    float a0 = p1[lane], a1 = p1[lane + 64];
    float b0 = p2[lane], b1 = p2[lane + 64];
    float dot = a0 * b0 + a1 * b1;
    float n1 = a0 * a0 + a1 * a1;
    float n2 = b0 * b0 + b1 * b1;
    for (int m = 32; m; m >>= 1) {
        dot += __shfl_xor(dot, m);
        n1  += __shfl_xor(n1, m);
        n2  += __shfl_xor(n2, m);
    }
    if (lane == 0) sim[b * 4096 + n] = dot / fmaxf(sqrtf(n1) * sqrtf(n2), 1e-8f);
}

// ---------------- x = concat(dif1, dif2) in [B][256][HW]
__global__ void x_kernel(const float* __restrict__ r1, const float* __restrict__ r2,
                         const float* __restrict__ sim, float* __restrict__ xo)
{
    size_t i = (size_t)blockIdx.x * 256 + threadIdx.x;
    int p = (int)(i & 4095);
    int cc = (int)((i >> 12) & 255);
    int b = (int)(i >> 20);
    int c = cc & 127;
    const float* R = (cc & 128) ? r2 : r1;
    const float* Rb = R + (size_t)b * 524288;
    float sv = sim[b * 4096 + p];
    xo[i] = Rb[(size_t)p * 128 + c] * (1.f - sv) + Rb[(size_t)c * 4096 + p];
}

// ---------------- attn = avgpool2(|sim1-sim2|) written directly as bf16 flat buffer
// (flat [b][c][h2][w2] layout == attn[b][n][c'] flat reinterpretation)
__global__ void simp_kernel(const float* __restrict__ r1, const float* __restrict__ r2,
                            const float* __restrict__ sim, unsigned short* __restrict__ attn_bf)
{
    int i = blockIdx.x * 256 + threadIdx.x;
    int w2 = i & 31, h2 = (i >> 5) & 31, c = (i >> 10) & 127, b = i >> 17;
    const float* R1 = r1 + (size_t)b * 524288;
    const float* R2 = r2 + (size_t)b * 524288;
    const float* sb = sim + b * 4096;
    float acc = 0.f;
    for (int dh = 0; dh < 2; ++dh)
        for (int dw = 0; dw < 2; ++dw) {
            int p = (2 * h2 + dh) * 64 + (2 * w2 + dw);
            float d = (R1[(size_t)p * 128 + c] - R2[(size_t)p * 128 + c]) * sb[p]
                    + (R1[(size_t)c * 4096 + p] - R2[(size_t)c * 4096 + p]);
            acc += fabsf(d);
        }
    attn_bf[i] = f2bf(acc * 0.25f);
}

// ---------------- attention pass A: per (pair, 16-row tile) compute row max and
// 1/rowsum of exp via online softmax over MFMA S tiles; fold 1/sum into attnS^T.
__global__ void __launch_bounds__(256)
attn_passA(const unsigned short* __restrict__ attn_bf,
           const unsigned short* __restrict__ incT1, const unsigned short* __restrict__ incT2,
           float* __restrict__ mx, unsigned short* __restrict__ attnS)
{
    __shared__ float lm[4][16], ls[4][16], srcp[16];
    int pair = blockIdx.y;          // pair = br*4 + b
    int b = pair & 3, br = pair >> 2;
    int tid = threadIdx.x;
    int wave = tid >> 6, lane = tid & 63;
    int n0 = blockIdx.x * 16;
    int q = lane >> 4, col = lane & 15;
    const unsigned short* arow = attn_bf + ((size_t)(b * 1024 + n0 + col)) * 128 + q * 8;
    short8 afr[4];
#pragma unroll
    for (int kc = 0; kc < 4; ++kc) afr[kc] = *(const short8*)(arow + kc * 32);
    const unsigned short* ib = (br ? incT2 : incT1) + (size_t)b * 524288;
    float rm[4], rsum[4];
#pragma unroll
    for (int r = 0; r < 4; ++r) { rm[r] = -3.0e38f; rsum[r] = 0.f; }
    for (int mt = 0; mt < 64; ++mt) {
        int m = wave * 1024 + mt * 16 + col;
        const unsigned short* brow = ib + (size_t)m * 128 + q * 8;
        floatx4 acc = (floatx4){0.f, 0.f, 0.f, 0.f};
#pragma unroll
        for (int kc = 0; kc < 4; ++kc) {
            short8 bfr = *(const short8*)(brow + kc * 32);
            acc = __builtin_amdgcn_mfma_f32_16x16x32_bf16(afr[kc], bfr, acc, 0, 0, 0);
        }
#pragma unroll
        for (int r = 0; r < 4; ++r) {
            float v = acc[r];
            float nm = fmaxf(rm[r], v);
            rsum[r] = rsum[r] * __expf(rm[r] - nm) + __expf(v - nm);
            rm[r] = nm;
        }
    }
    // reduce across the 16 lanes sharing q (they hold different m columns)
#pragma unroll
    for (int d = 1; d < 16; d <<= 1) {
#pragma unroll
        for (int r = 0; r < 4; ++r) {
            float om = __shfl_xor(rm[r], d);
            float os = __shfl_xor(rsum[r], d);
            float nm = fmaxf(rm[r], om);
            rsum[r] = rsum[r] * __expf(rm[r] - nm) + os * __expf(om - nm);
            rm[r] = nm;
        }
    }
    if (col == 0) {
#pragma unroll
        for (int r = 0; r < 4; ++r) { lm[wave][q * 4 + r] = rm[r]; ls[wave][q * 4 + r] = rsum[r]; }
    }
    __syncthreads();
    if (tid < 16) {
        float nm = lm[0][tid];
        for (int w = 1; w < 4; ++w) nm = fmaxf(nm, lm[w][tid]);
        float ssum = 0.f;
        for (int w = 0; w < 4; ++w) ssum += ls[w][tid] * __expf(lm[w][tid] - nm);
        mx[pair * 1024 + n0 + tid] = nm;
        srcp[tid] = 1.f / ssum;
    }
    __syncthreads();
    // attnS[pair][c][n] = attn[n][c] * rcp[n]  (bf16) for this block's 16 rows
    {
        int n = tid & 15, c0 = (tid >> 4) * 8;
        float rc = srcp[n];
        const unsigned short* ap = attn_bf + ((size_t)(b * 1024 + n0 + n)) * 128 + c0;
        unsigned short* sp = attnS + (size_t)pair * 131072 + (size_t)c0 * 1024 + n0 + n;
#pragma unroll
        for (int j = 0; j < 8; ++j)
            sp[(size_t)j * 1024] = f2bf(bf2f(ap[j]) * rc);
    }
}

// ---------------- attention pass B: recompute S tile, P=exp(S-mx), LDS layout
// transform, contract with attnS^T -> out[c][m] + residual -> abuf.
__global__ void __launch_bounds__(256)
attn_passB(const unsigned short* __restrict__ attn_bf,
           const unsigned short* __restrict__ attnS,
           const unsigned short* __restrict__ incT1, const unsigned short* __restrict__ incT2,
           const float* __restrict__ mx,
           const float* __restrict__ inc1f, const float* __restrict__ inc2f,
           float* __restrict__ abuf)
{
    __shared__ unsigned short lp[4][16 * 40];   // per wave: [m=16][n=32 + 8 pad]
    int pair = blockIdx.y;
    int b = pair & 3, br = pair >> 2;
    int tid = threadIdx.x;
    int wave = tid >> 6, lane = tid & 63;
    int q = lane >> 4, col = lane & 15;
    int m0 = blockIdx.x * 64 + wave * 16;
    const unsigned short* ib = (br ? incT2 : incT1) + (size_t)b * 524288 + (size_t)(m0 + col) * 128 + q * 8;
    short8 bfrS[4];
#pragma unroll
    for (int kc = 0; kc < 4; ++kc) bfrS[kc] = *(const short8*)(ib + kc * 32);
    const float* mxp = mx + pair * 1024;
    const unsigned short* asb = attnS + (size_t)pair * 131072;
    floatx4 oacc[8];
#pragma unroll
    for (int ct = 0; ct < 8; ++ct) oacc[ct] = (floatx4){0.f, 0.f, 0.f, 0.f};
    unsigned short* lw = lp[wave];
    for (int nc = 0; nc < 32; ++nc) {
#pragma unroll
        for (int t = 0; t < 2; ++t) {
            int n0 = nc * 32 + t * 16;
            const unsigned short* ar = attn_bf + ((size_t)(b * 1024 + n0 + col)) * 128 + q * 8;
            floatx4 sacc = (floatx4){0.f, 0.f, 0.f, 0.f};
#pragma unroll
            for (int kc = 0; kc < 4; ++kc)
                sacc = __builtin_amdgcn_mfma_f32_16x16x32_bf16(*(const short8*)(ar + kc * 32), bfrS[kc], sacc, 0, 0, 0);
            unsigned int p01, p23;
            {
                float e0 = __expf(sacc[0] - mxp[n0 + q * 4 + 0]);
                float e1 = __expf(sacc[1] - mxp[n0 + q * 4 + 1]);
                float e2 = __expf(sacc[2] - mxp[n0 + q * 4 + 2]);
                float e3 = __expf(sacc[3] - mxp[n0 + q * 4 + 3]);
                p01 = (unsigned int)f2bf(e0) | ((unsigned int)f2bf(e1) << 16);
                p23 = (unsigned int)f2bf(e2) | ((unsigned int)f2bf(e3) << 16);
            }
            // LDS [m=col][n_local = t*16 + q*4 .. +3]
            uint2* dst = (uint2*)&lw[col * 40 + t * 16 + q * 4];
            *dst = make_uint2(p01, p23);
        }
        // B-frag: P[k=q*8+j][m=col]
        short8 pb = *(const short8*)&lw[col * 40 + q * 8];
#pragma unroll
        for (int ct = 0; ct < 8; ++ct) {
            const unsigned short* asr = asb + (size_t)(ct * 16 + col) * 1024 + nc * 32 + q * 8;
            oacc[ct] = __builtin_amdgcn_mfma_f32_16x16x32_bf16(*(const short8*)asr, pb, oacc[ct], 0, 0, 0);
        }
    }
    const float* incp = (br ? inc2f : inc1f) + (size_t)b * 524288;
    float* op = abuf + ((size_t)(b * 256 + br * 128)) * 4096;
    int m = m0 + col;
#pragma unroll
    for (int ct = 0; ct < 8; ++ct)
#pragma unroll
        for (int r = 0; r < 4; ++r) {
            int c = ct * 16 + q * 4 + r;
            op[(size_t)c * 4096 + m] = oacc[ct][r] + incp[(size_t)c * 4096 + m];
        }
}

// ---------------- bilinear 2x upsample, half-pixel centers, edge clamp
__global__ void upsample_kernel(const float* __restrict__ in, float* __restrict__ out)
{
    int i = blockIdx.x * 256 + threadIdx.x;
    int x = i & 127, y = (i >> 7) & 127, bc = i >> 14;
    const float* ib = in + (size_t)bc * HW;
    float sy = 0.5f * y - 0.25f;
    float sx = 0.5f * x - 0.25f;
    int y0 = (int)floorf(sy); float ty = sy - y0;
    int x0 = (int)floorf(sx); float tx = sx - x0;
    int y0c = min(max(y0, 0), 63), y1c = min(max(y0 + 1, 0), 63);
    int x0c = min(max(x0, 0), 63), x1c = min(max(x0 + 1, 0), 63);
    float v00 = ib[y0c * 64 + x0c], v01 = ib[y0c * 64 + x1c];
    float v10 = ib[y1c * 64 + x0c], v11 = ib[y1c * 64 + x1c];
    out[i] = (1.f - ty) * ((1.f - tx) * v00 + tx * v01) + ty * ((1.f - tx) * v10 + tx * v11);
}

extern "C" void kernel_launch(void* const* d_in, const int* in_sizes, int n_in,
                              void* d_out, int out_size, void* d_ws, size_t ws_size,
                              hipStream_t stream)
{
    const float* t1       = (const float*)d_in[0];
    const float* t2       = (const float*)d_in[1];
    const float* t1_w     = (const float*)d_in[2];
    const float* t1_b     = (const float*)d_in[3];
    const float* t2_w     = (const float*)d_in[4];
    const float* t2_b     = (const float*)d_in[5];
    const float* df_res_w = (const float*)d_in[6];
    const float* df_res_b = (const float*)d_in[7];
    const float* df_res_s = (const float*)d_in[8];
    const float* df_res_o = (const float*)d_in[9];
    const float* df_b0_w  = (const float*)d_in[10];
    const float* df_b0_b  = (const float*)d_in[11];
    const float* df_b0_s  = (const float*)d_in[12];
    const float* df_b0_o  = (const float*)d_in[13];
    const float* df_b1_w  = (const float*)d_in[14];
    const float* df_b1_b  = (const float*)d_in[15];
    const float* df_b1_s  = (const float*)d_in[16];
    const float* df_b1_o  = (const float*)d_in[17];
    const float* df_fu_w  = (const float*)d_in[18];
    const float* df_fu_b  = (const float*)d_in[19];
    const float* df_fu_s  = (const float*)d_in[20];
    const float* df_fu_o  = (const float*)d_in[21];
    const float* br1_w    = (const float*)d_in[22];
    const float* br1_b    = (const float*)d_in[23];
    const float* br2_w    = (const float*)d_in[24];
    const float* br2_b    = (const float*)d_in[25];
    const float* fu_w     = (const float*)d_in[26];
    const float* fu_b     = (const float*)d_in[27];
    const float* fu_s     = (const float*)d_in[28];
    const float* fu_o     = (const float*)d_in[29];

    float* ws = (float*)d_ws;
    float* res1 = ws;                   // 2,097,152 f  (res1 -> r -> inc1 fp32)
    float* res2 = ws + 2097152;         // 2,097,152 f  (res2 -> b01 -> inc2 fp32)
    float* xbuf = ws + 4194304;         // 4,194,304 f  (x -> dif; fused at +2M)
    float* scr  = ws + 8388608;         // 4,194,304 f  bf16 scratch region
    float* abuf = ws + 12582912;        // 4,194,304 f  concat(a1,a2)
    float* attnS_f = ws + 16777216;     // 524,288 f -> attnS bf16 (1,048,576 u16)
    float* simv = ws + 17301504;        // 16,384 f
    float* mxb  = ws + 17317888;        // 8,192 f

    // bf16 scratch layout (u16 offsets within scr)
    unsigned short* us     = (unsigned short*)scr;
    unsigned short* wp_b0  = us;                 // 73,728
    unsigned short* wp_b1  = us + 73728;         // 204,800
    unsigned short* wp_br1 = us + 278528;        // 147,456
    unsigned short* wp_br2 = us + 425984;        // 409,600 -> ends 835,584
    unsigned short* xt_r   = us + 851968;        // 2,367,488 -> ends 3,219,456
    unsigned short* xt_dif = us + 3219456;       // 2,367,488 -> ends 5,586,944
    unsigned short* incT1  = us + 5586944;       // 2,097,152 -> ends 7,684,096
    unsigned short* incT2  = us + 851968;        // 2,097,152 (overlays dead xt_r)
    unsigned short* attn_bf= us + 7684096;       // 524,288 -> ends 8,208,384
    unsigned short* attnS  = (unsigned short*)attnS_f;

    dim3 blk(256);

    // zero padded bf16 conv inputs (xt_r + xt_dif); prepack conv weights
    zero_kernel<<<2312, blk, 0, stream>>>((uint4*)xt_r, 591872);
    prepack_w<<<288,  blk, 0, stream>>>(df_b0_w, wp_b0, 64, 128, 9);
    prepack_w<<<800,  blk, 0, stream>>>(df_b1_w, wp_b1, 64, 128, 25);
    prepack_w<<<576,  blk, 0, stream>>>(br1_w, wp_br1, 128, 128, 9);
    prepack_w<<<1600, blk, 0, stream>>>(br2_w, wp_br2, 128, 128, 25);

    // res1/res2 = 1x1 conv(t1/t2)
    conv1x1_tiled<<<dim3(16, 8, 4), blk, 0, stream>>>(t1, t1_w, t1_b, res1, 256, 128, 0, nullptr, nullptr, nullptr, nullptr);
    conv1x1_tiled<<<dim3(16, 8, 4), blk, 0, stream>>>(t2, t2_w, t2_b, res2, 256, 128, 0, nullptr, nullptr, nullptr, nullptr);
    sim_kernel<<<4096, blk, 0, stream>>>(res1, res2, simv);
    x_kernel<<<16384, blk, 0, stream>>>(res1, res2, simv, xbuf);
    simp_kernel<<<2048, blk, 0, stream>>>(res1, res2, simv, attn_bf);
    // r = stdconv1x1(x) -> res1 (+ bf16 padded copy)
    conv1x1_tiled<<<dim3(16, 8, 4), blk, 0, stream>>>(xbuf, df_res_w, df_res_b, res1, 256, 128, 1, df_res_s, df_res_o, nullptr, xt_r);
    // b0 3x3 -> res2[0:64], b1 5x5 -> res2[64:128]
    convk_mfma<3, 64, 1><<<dim3(64, 4), blk, 0, stream>>>(xt_r, wp_b0, df_b0_b, res2, 128, 0, 1, df_b0_s, df_b0_o, nullptr);
    convk_mfma<5, 64, 1><<<dim3(64, 4), blk, 0, stream>>>(xt_r, wp_b1, df_b1_b, res2, 128, 64, 1, df_b1_s, df_b1_o, nullptr);
    // dif = stdconv1x1(b01) + r -> xbuf (+ bf16 padded copy); xt_r dead after this point's convs
    conv1x1_tiled<<<dim3(16, 8, 4), blk, 0, stream>>>(res2, df_fu_w, df_fu_b, xbuf, 128, 128, 1, df_fu_s, df_fu_o, res1, xt_dif);
    // inc1/inc2 (fp32 + bf16 transposed incT)
    convk_mfma<3, 128, 2><<<dim3(64, 4), blk, 0, stream>>>(xt_dif, wp_br1, br1_b, res1, 128, 0, 0, nullptr, nullptr, incT1);
    convk_mfma<5, 128, 2><<<dim3(64, 4), blk, 0, stream>>>(xt_dif, wp_br2, br2_b, res2, 128, 0, 0, nullptr, nullptr, incT2);
    // attention: pass A (row max + 1/sum + prescaled attnS), pass B (recompute+contract)
    attn_passA<<<dim3(64, 8), blk, 0, stream>>>(attn_bf, incT1, incT2, mxb, attnS);
    attn_passB<<<dim3(64, 8), blk, 0, stream>>>(attn_bf, attnS, incT1, incT2, mxb, res1, res2, abuf);
    // fused = stdconv1x1(concat(a1,a2)) + dif
    float* dif = xbuf;
    float* fused = xbuf + 2097152;
    conv1x1_tiled<<<dim3(16, 8, 4), blk, 0, stream>>>(abuf, fu_w, fu_b, fused, 256, 128, 1, fu_s, fu_o, dif, nullptr);
    // bilinear 2x upsample -> d_out
    upsample_kernel<<<32768, blk, 0, stream>>>(fused, (float*)d_out);
}